// Round 18
// baseline (39.097 us; speedup 1.0000x reference)
//
#include <hip/hip_runtime.h>
#include <stdint.h>

#define NXP   2048   // pivotal (source) nodes
#define NC    16     // feature channels
#define GD    8      // grid cells per axis
#define NCELL (GD*GD*GD)   // 512
#define CAP   512    // max staged candidates per cell block
#define QCAP  512    // query LDS list capacity per pass
#define HCELL 0.125f
#define NQB   128    // query scatter blocks
#define BQ    512    // queries per scatter block

// ---- d_ws layout (bytes); total 305472 <= 312832 (proven available, r9) ----
#define WS_SPT   0        // float4[2048]
#define WS_SIDX  32768    // int[2048]
#define WS_CST   40960    // int[513]                     (ends 43012)
#define WS_SCN   43072    // u16[128][513] per-block cell scan (ends 174400)
#define WS_QSRT  174400   // u16[65536] block-sorted query ids (ends 305472)
#define WS_NEED  305472

__device__ __forceinline__ int cell_of(float v) {
    int c = (int)(v * (float)GD);
    c = c > GD - 1 ? GD - 1 : c;
    return c < 0 ? 0 : c;
}
__device__ __forceinline__ uint32_t mono(float d) {
    uint32_t b = __float_as_uint(d);
    return b ^ (uint32_t)(((int32_t)b >> 31) | 0x80000000);
}
__device__ __forceinline__ float unmono(uint32_t m) {
    uint32_t b = (m & 0x80000000u) ? (m ^ 0x80000000u) : ~m;
    return __uint_as_float(b);
}
__device__ __forceinline__ void ins_fast(uint64_t k, uint64_t& b0, uint64_t& b1, uint64_t& b2) {
    const bool lt0 = k < b0, lt1 = k < b1;
    b2 = lt1 ? b1 : k;
    b1 = lt0 ? b0 : (lt1 ? k : b1);
    b0 = lt0 ? k  : b0;
}
__device__ __forceinline__ void ins_dedup(uint64_t k, uint64_t& b0, uint64_t& b1, uint64_t& b2) {
    if (k == b0 || k == b1 || k == b2) return;
    const bool lt0 = k < b0, lt1 = k < b1, lt2 = k < b2;
    b2 = lt1 ? b1 : (lt2 ? k : b2);
    b1 = lt0 ? b0 : (lt1 ? k : b1);
    b0 = lt0 ? k  : b0;
}
__device__ __forceinline__ uint64_t shfl_u64(uint64_t v, int src) {
    const int lo = __shfl((int)(uint32_t)v, src);
    const int hi = __shfl((int)(uint32_t)(v >> 32), src);
    return ((uint64_t)(uint32_t)hi << 32) | (uint32_t)lo;
}
__device__ __forceinline__ uint64_t shfl_xor_u64(uint64_t v, int mask) {
    const int lo = __shfl_xor((int)(uint32_t)v, mask);
    const int hi = __shfl_xor((int)(uint32_t)(v >> 32), mask);
    return ((uint64_t)(uint32_t)hi << 32) | (uint32_t)lo;
}

// ========== K1: block 0 builds point grid; blocks 1..128 LDS-sort queries ==========
__global__ __launch_bounds__(512) void build_scatter(
    const float* __restrict__ pos_x, const float* __restrict__ pos_y, int ny,
    float4* __restrict__ wspt, int* __restrict__ wsidx, int* __restrict__ wcstart,
    unsigned short* __restrict__ scan2d, unsigned short* __restrict__ qsrt)
{
    __shared__ int sA[NCELL];
    __shared__ int sB[NCELL];
    const int t = threadIdx.x;

    if (blockIdx.x == 0) {
        // ---- point grid build (byte-identical to proven r6..r17 code) ----
        sA[t] = 0;
        __syncthreads();

        const float4* px4 = (const float4*)pos_x;
        const float4 v0 = px4[t*3+0], v1 = px4[t*3+1], v2 = px4[t*3+2];
        const float pxx[4] = {v0.x, v0.w, v1.z, v2.y};
        const float pyy[4] = {v0.y, v1.x, v1.w, v2.z};
        const float pzz[4] = {v0.z, v1.y, v2.x, v2.w};
        int cc[4];
        #pragma unroll
        for (int i = 0; i < 4; ++i) {
            cc[i] = (cell_of(pzz[i]) * GD + cell_of(pyy[i])) * GD + cell_of(pxx[i]);
            atomicAdd(&sA[cc[i]], 1);
        }
        __syncthreads();

        if (t < 64) {
            const int base = t * 8;
            int v[8];
            int run = 0;
            #pragma unroll
            for (int i = 0; i < 8; ++i) { run += sA[base + i]; v[i] = run; }
            int xs = run;
            #pragma unroll
            for (int off = 1; off < 64; off <<= 1) {
                const int y = __shfl_up(xs, off);
                if (t >= off) xs += y;
            }
            const int excl = xs - run;
            #pragma unroll
            for (int i = 0; i < 8; ++i) {
                const int inc = excl + v[i];
                wcstart[base + i + 1] = inc;
                sB[base + i] = inc - sA[base + i];
            }
            if (t == 0) wcstart[0] = 0;
        }
        __syncthreads();

        #pragma unroll
        for (int i = 0; i < 4; ++i) {
            const int p = t * 4 + i;
            const int pos = atomicAdd(&sB[cc[i]], 1);
            const float sx = __fadd_rn(__fadd_rn(__fmul_rn(pxx[i], pxx[i]),
                                                 __fmul_rn(pyy[i], pyy[i])),
                                       __fmul_rn(pzz[i], pzz[i]));
            wspt[pos] = make_float4(pxx[i], pyy[i], pzz[i], sx);
            wsidx[pos] = p;
        }
    } else {
        // ---- LDS counting sort of this block's 512 queries (no global atomics) ----
        const int b = blockIdx.x - 1;
        sA[t] = 0;
        __syncthreads();

        const int q = b * BQ + t;
        int c = -1;
        if (q < ny) {
            c = (cell_of(pos_y[q*3+2]) * GD + cell_of(pos_y[q*3+1])) * GD
              + cell_of(pos_y[q*3+0]);
            atomicAdd(&sA[c], 1);     // LDS atomic
        }
        __syncthreads();

        if (t < 64) {
            const int base = t * 8;
            int v[8];
            int run = 0;
            #pragma unroll
            for (int i = 0; i < 8; ++i) { run += sA[base + i]; v[i] = run; }
            int xs = run;
            #pragma unroll
            for (int off = 1; off < 64; off <<= 1) {
                const int y = __shfl_up(xs, off);
                if (t >= off) xs += y;
            }
            const int excl = xs - run;
            #pragma unroll
            for (int i = 0; i < 8; ++i)
                sB[base + i] = excl + v[i] - sA[base + i];   // exclusive start
        }
        __syncthreads();

        scan2d[b * 513 + t] = (unsigned short)sB[t];
        if (t == 0) {
            int nb = ny - b * BQ;
            nb = nb < 0 ? 0 : (nb > BQ ? BQ : nb);
            scan2d[b * 513 + 512] = (unsigned short)nb;
        }
        __syncthreads();

        if (q < ny) {
            const int pos = atomicAdd(&sB[c], 1);   // LDS atomic rank
            qsrt[b * BQ + pos] = (unsigned short)q;
        }
    }
}

// ========== K2: TWO blocks per cell, 512 threads, 8-lane group per query ==========
__global__ __launch_bounds__(512) void knn_cell(
    const float* __restrict__ x, const float* __restrict__ pos_x,
    const float* __restrict__ pos_y,
    const float4* __restrict__ wspt, const int* __restrict__ wsidx,
    const int* __restrict__ wcst,
    const unsigned short* __restrict__ scan2d, const unsigned short* __restrict__ qsrt,
    float* __restrict__ out)
{
    __shared__ float4 scand[CAP];
    __shared__ int    scidx[CAP];
    __shared__ int    rst[25], roff[26];
    __shared__ int    sL, sForce;
    __shared__ unsigned short qlist[QCAP];
    __shared__ int    wsum[2];

    const int t = threadIdx.x;
    const int c = blockIdx.x >> 1, half = blockIdx.x & 1;
    const int cx = c & 7, cy = (c >> 3) & 7, cz = c >> 6;
    const int lane = t & 63;   // lane in wave
    const int grp  = t >> 3;   // query group 0..63
    const int s    = t & 7;    // segment within group

    // R=2 only for edge/corner cells (bcnt>=2) — r6/r7-proven rule
    const int bcnt = (int)(cx == 0 || cx == GD-1) + (int)(cy == 0 || cy == GD-1)
                   + (int)(cz == 0 || cz == GD-1);
    const int R  = (bcnt >= 2) ? 2 : 1;
    const int W  = 2 * R + 1;
    const int NR = W * W;

    if (t < NR) {
        const int uz = cz + t / W - R, uy = cy + t % W - R;
        int st = 0, len = 0;
        if (((unsigned)uz < (unsigned)GD) & ((unsigned)uy < (unsigned)GD)) {
            const int xa = cx - R < 0 ? 0 : cx - R;
            const int xb = cx + R > GD - 1 ? GD - 1 : cx + R;
            const int cb = (uz * GD + uy) * GD;
            st  = wcst[cb + xa];
            len = wcst[cb + xb + 1] - st;
        }
        rst[t] = st;
        roff[t] = len;
    }
    __syncthreads();
    if (t == 0) {
        int o = 0;
        #pragma unroll 1
        for (int r = 0; r < NR; ++r) { const int l = roff[r]; roff[r] = o; o += l; }
        roff[NR] = o;
        sL = o > CAP ? CAP : o;
        sForce = (o > CAP) ? 1 : 0;
    }
    __syncthreads();

    // Lpad multiple of 64 (per-lane count multiple of 8); max (512+63)&~63 == 512 <= CAP
    const int L = sL, Lpad = (sL + 63) & ~63, force = sForce;
    for (int i = t; i < L; i += 512) {
        int r = 0;
        while (i >= roff[r + 1]) ++r;
        const int src = rst[r] + (i - roff[r]);
        scand[i] = wspt[src];
        scidx[i] = wsidx[src];
    }
    for (int i = L + t; i < Lpad; i += 512) {
        scand[i] = make_float4(0.f, 0.f, 0.f, 3e30f);  // sentinel: never inserted
        scidx[i] = 0x7fffffff;
    }

    // ---- query gather (threads 0..127): lane t = source block; seg [s0, s0+cnt) ----
    int base = 0, cnt = 0, s0 = 0;
    if (t < 128) {
        s0  = (int)scan2d[t * 513 + c];
        cnt = (int)scan2d[t * 513 + c + 1] - s0;
        int inc = cnt;
        #pragma unroll
        for (int off = 1; off < 64; off <<= 1) {
            const int y = __shfl_up(inc, off);
            if (lane >= off) inc += y;
        }
        if (lane == 63) wsum[t >> 6] = inc;
        base = inc - cnt;
    }
    __syncthreads();
    if (t >= 64 && t < 128) base += wsum[0];
    const int total = wsum[0] + wsum[1];

    // this block handles [beg, end) of the cell's query list
    const int mid = (total + 1) >> 1;
    const int beg = half ? mid : 0;
    const int end = half ? total : mid;

    for (int S = 0; S < total; S += QCAP) {
        __syncthreads();
        if (t < 128) {
            for (int k = 0; k < cnt; ++k) {
                const int g = base + k;
                if (g >= S && g < S + QCAP) qlist[g - S] = qsrt[t * BQ + s0 + k];
            }
        }
        __syncthreads();
        // intersect this chunk with [beg, end)
        const int n   = (total - S) < QCAP ? (total - S) : QCAP;
        const int lo  = (beg - S) > 0 ? (beg - S) : 0;
        const int hi  = (end - S) < n ? (end - S) : n;

        for (int i0 = lo; i0 < hi; i0 += 64) {
            const int slot = i0 + grp;
            const bool active = slot < hi;
            const int q = active ? (int)qlist[slot] : 0;
            float y0 = 0.f, y1 = 0.f, y2 = 0.f;
            if (active) { y0 = pos_y[q*3+0]; y1 = pos_y[q*3+1]; y2 = pos_y[q*3+2]; }
            const float sy = __fadd_rn(__fadd_rn(__fmul_rn(y0, y0), __fmul_rn(y1, y1)),
                                       __fmul_rn(y2, y2));

            // exact clearance to staged cube (proven r9..r17)
            float clr = 1e30f;
            if (cx - R > 0)      clr = fminf(clr, y0 - (float)(cx - R) * HCELL);
            if (cx + R < GD - 1) clr = fminf(clr, (float)(cx + R + 1) * HCELL - y0);
            if (cy - R > 0)      clr = fminf(clr, y1 - (float)(cy - R) * HCELL);
            if (cy + R < GD - 1) clr = fminf(clr, (float)(cy + R + 1) * HCELL - y1);
            if (cz - R > 0)      clr = fminf(clr, y2 - (float)(cz - R) * HCELL);
            if (cz + R < GD - 1) clr = fminf(clr, (float)(cz + R + 1) * HCELL - y2);
            const float thr = clr * clr;

            uint64_t b0 = ~0ull, b1 = ~0ull, b2 = ~0ull;

            // ---- phase A: lane scans its eighth (stride-8 interleave),
            // 2-deep pipeline over 4-candidate batches; d2 rounding identical
            // to every passing round.
            const int PL = Lpad >> 3;    // per-lane candidates, multiple of 8
            float4 pA[4]; int iA[4];
            float4 pB[4]; int iB[4];
            #pragma unroll
            for (int u = 0; u < 4; ++u) {
                const int id = s + 8*u;
                pA[u] = scand[id]; iA[u] = scidx[id];
            }

            for (int j = 0; j < PL; j += 8) {
                #pragma unroll
                for (int u = 0; u < 4; ++u) {
                    const int id = s + 8*(j + 4 + u);
                    pB[u] = scand[id]; iB[u] = scidx[id];
                }
                {
                    uint64_t kk[4];
                    #pragma unroll
                    for (int u = 0; u < 4; ++u) {
                        const float dot = __fmaf_rn(y2, pA[u].z,
                                          __fmaf_rn(y1, pA[u].y, __fmul_rn(y0, pA[u].x)));
                        const float d = __fmaf_rn(-2.0f, dot, __fadd_rn(sy, pA[u].w));
                        kk[u] = ((uint64_t)mono(d) << 32) | (uint32_t)iA[u];
                    }
                    #pragma unroll
                    for (int u = 0; u < 4; ++u) {
                        const uint64_t k2 = kk[u];
                        const bool lt0 = k2 < b0, lt1 = k2 < b1, lt2 = k2 < b2;
                        b2 = lt1 ? b1 : (lt2 ? k2 : b2);
                        b1 = lt0 ? b0 : (lt1 ? k2 : b1);
                        b0 = lt0 ? k2 : b0;
                    }
                }
                if (j + 8 < PL) {
                    #pragma unroll
                    for (int u = 0; u < 4; ++u) {
                        const int id = s + 8*(j + 8 + u);
                        pA[u] = scand[id]; iA[u] = scidx[id];
                    }
                }
                {
                    uint64_t kk[4];
                    #pragma unroll
                    for (int u = 0; u < 4; ++u) {
                        const float dot = __fmaf_rn(y2, pB[u].z,
                                          __fmaf_rn(y1, pB[u].y, __fmul_rn(y0, pB[u].x)));
                        const float d = __fmaf_rn(-2.0f, dot, __fadd_rn(sy, pB[u].w));
                        kk[u] = ((uint64_t)mono(d) << 32) | (uint32_t)iB[u];
                    }
                    #pragma unroll
                    for (int u = 0; u < 4; ++u) {
                        const uint64_t k2 = kk[u];
                        const bool lt0 = k2 < b0, lt1 = k2 < b1, lt2 = k2 < b2;
                        b2 = lt1 ? b1 : (lt2 ? k2 : b2);
                        b1 = lt0 ? b0 : (lt1 ? k2 : b1);
                        b0 = lt0 ? k2 : b0;
                    }
                }
            }

            // merge across the 8-lane group (masks 1,2,4 stay in-group); dedup
            // makes overlap-free merging safe (r5-proven)
            #pragma unroll
            for (int mask = 1; mask < 8; mask <<= 1) {
                const uint64_t r0 = shfl_xor_u64(b0, mask);
                const uint64_t r1 = shfl_xor_u64(b1, mask);
                const uint64_t r2 = shfl_xor_u64(b2, mask);
                ins_dedup(r0, b0, b1, b2);
                ins_dedup(r1, b0, b1, b2);
                ins_dedup(r2, b0, b1, b2);
            }

            // escalation (proven): only group leader flags; wave-coop brute
            bool esc = false;
            if (active && s == 0) {
                const bool have3 = (b2 != ~0ull);
                const float b2d = unmono((uint32_t)(b2 >> 32));
                esc = !(have3 && (b2d + 1e-4f < thr)) | (force != 0);
            }
            unsigned long long bal = __ballot(esc);
            while (bal) {
                const int e = __ffsll(bal) - 1;
                bal &= bal - 1;
                const float ey0 = __shfl(y0, e), ey1 = __shfl(y1, e), ey2 = __shfl(y2, e);
                const float esy = __shfl(sy, e);
                uint64_t m0 = shfl_u64(b0, e), m1 = shfl_u64(b1, e), m2 = shfl_u64(b2, e);
                for (int p = lane; p < NXP; p += 64) {
                    const float4 pt = wspt[p];
                    const float dot = __fmaf_rn(ey2, pt.z,
                                      __fmaf_rn(ey1, pt.y, __fmul_rn(ey0, pt.x)));
                    const float d = __fmaf_rn(-2.0f, dot, __fadd_rn(esy, pt.w));
                    const uint64_t kk = ((uint64_t)mono(d) << 32) | (uint32_t)wsidx[p];
                    if (kk < m2) ins_dedup(kk, m0, m1, m2);
                }
                #pragma unroll
                for (int mask = 1; mask < 64; mask <<= 1) {
                    const uint64_t r0 = shfl_xor_u64(m0, mask);
                    const uint64_t r1 = shfl_xor_u64(m1, mask);
                    const uint64_t r2 = shfl_xor_u64(m2, mask);
                    ins_dedup(r0, m0, m1, m2);
                    ins_dedup(r1, m0, m1, m2);
                    ins_dedup(r2, m0, m1, m2);
                }
                if (lane == e) { b0 = m0; b1 = m1; b2 = m2; }
            }
            // re-broadcast group leader's triple (identity for non-escalated)
            {
                const int ldr = lane & ~7;
                b0 = shfl_u64(b0, ldr);
                b1 = shfl_u64(b1, ldr);
                b2 = shfl_u64(b2, ldr);
            }

            // epilogue: each lane writes channel pair s (coalesced 64B/query)
            if (active) {
                const int j0 = (int)(uint32_t)b0, j1 = (int)(uint32_t)b1,
                          j2 = (int)(uint32_t)b2;
                float w[3];
                const int jj[3] = { j0, j1, j2 };
                #pragma unroll
                for (int i = 0; i < 3; ++i) {
                    const float dx = __fsub_rn(pos_x[jj[i]*3+0], y0);
                    const float dy = __fsub_rn(pos_x[jj[i]*3+1], y1);
                    const float dz = __fsub_rn(pos_x[jj[i]*3+2], y2);
                    const float sq = __fadd_rn(__fadd_rn(__fmul_rn(dx, dx),
                                                         __fmul_rn(dy, dy)),
                                               __fmul_rn(dz, dz));
                    w[i] = 1.0f / fmaxf(sq, 1e-16f);
                }
                const float inv_den = 1.0f / __fadd_rn(__fadd_rn(w[0], w[1]), w[2]);
                const float2* x2 = (const float2*)x;   // row stride = 8 float2
                float2* o2 = (float2*)out;
                const float2 a = x2[j0*8 + s];
                const float2 b = x2[j1*8 + s];
                const float2 cc2 = x2[j2*8 + s];
                float2 r;
                r.x = (w[0]*a.x + w[1]*b.x + w[2]*cc2.x) * inv_den;
                r.y = (w[0]*a.y + w[1]*b.y + w[2]*cc2.y) * inv_den;
                o2[q*8 + s] = r;
            }
        }
    }
}

// =============== fallback (round-7 kernel, 43 KB ws; proven 34 us) ===============
#define QBLK  512
#define SEG   8
#define QPB   (QBLK / SEG)
#define QGRID 512

__device__ __forceinline__ void merge_group8(uint64_t& b0, uint64_t& b1, uint64_t& b2) {
    #pragma unroll
    for (int mask = 1; mask < SEG; mask <<= 1) {
        const uint64_t r0 = shfl_xor_u64(b0, mask);
        const uint64_t r1 = shfl_xor_u64(b1, mask);
        const uint64_t r2 = shfl_xor_u64(b2, mask);
        ins_dedup(r0, b0, b1, b2);
        ins_dedup(r1, b0, b1, b2);
        ins_dedup(r2, b0, b1, b2);
    }
}

__global__ __launch_bounds__(QBLK) void knn_query_fb(
    const float* __restrict__ x, const float* __restrict__ pos_x,
    const float* __restrict__ pos_y,
    const float4* __restrict__ wspt, const int* __restrict__ wsidx,
    const int* __restrict__ wcstart,
    float* __restrict__ out, int ny)
{
    __shared__ float4 spt[NXP];
    __shared__ int    sidx[NXP];
    __shared__ int    cstart[NCELL + 1];

    const int t = threadIdx.x;
    for (int i = t; i < NXP; i += QBLK) spt[i] = wspt[i];
    for (int i = t; i < NXP; i += QBLK) sidx[i] = wsidx[i];
    for (int i = t; i < NCELL + 1; i += QBLK) cstart[i] = wcstart[i];
    __syncthreads();

    const int s = t & (SEG - 1);
    const int nbatch = (ny + QPB - 1) / QPB;

    for (int batch = blockIdx.x; batch < nbatch; batch += gridDim.x) {
        const int q = batch * QPB + (t >> 3);
        if (q >= ny) continue;

        const float y0 = pos_y[q*3+0], y1 = pos_y[q*3+1], y2 = pos_y[q*3+2];
        const float sy = __fadd_rn(__fadd_rn(__fmul_rn(y0, y0), __fmul_rn(y1, y1)),
                                   __fmul_rn(y2, y2));
        const int cx = cell_of(y0), cy = cell_of(y1), cz = cell_of(y2);

        uint64_t b0 = ~0ull, b1 = ~0ull, b2 = ~0ull;

#define EVAL_BODY(P, INS)                                                       \
        {                                                                       \
            const float4 pt = spt[P];                                           \
            const float dot = __fmaf_rn(y2, pt.z,                               \
                              __fmaf_rn(y1, pt.y, __fmul_rn(y0, pt.x)));        \
            const float d = __fmaf_rn(-2.0f, dot, __fadd_rn(sy, pt.w));         \
            const uint64_t kk = ((uint64_t)mono(d) << 32) | (uint32_t)sidx[P];  \
            if (kk < b2) INS(kk, b0, b1, b2);                                   \
        }

        const int x0 = cx - 1 < 0 ? 0 : cx - 1;
        const int x1 = cx + 1 > GD - 1 ? GD - 1 : cx + 1;
        #pragma unroll
        for (int r = 0; r < 9; ++r) {
            const int uz = cz + r / 3 - 1, uy = cy + r % 3 - 1;
            int st = 0, en = 0;
            if (((unsigned)uz < (unsigned)GD) & ((unsigned)uy < (unsigned)GD)) {
                const int cb = (uz * GD + uy) * GD;
                st = cstart[cb + x0];
                en = cstart[cb + x1 + 1];
            }
            for (int p = st + s; p < en; p += SEG) EVAL_BODY(p, ins_fast)
        }
        merge_group8(b0, b1, b2);

        {
            bool have3 = (b2 != ~0ull);
            float b2d = unmono((uint32_t)(b2 >> 32));
            if (!(have3 && (b2d + 1e-4f < 0.015625f))) {
                for (int r = 0; r < 25; ++r) {
                    const int dzi = r / 5 - 2, dyi = r % 5 - 2;
                    const int uz = cz + dzi, uy = cy + dyi;
                    if (((unsigned)uz >= (unsigned)GD) | ((unsigned)uy >= (unsigned)GD))
                        continue;
                    const int cb = (uz * GD + uy) * GD;
                    if (dzi == -2 || dzi == 2 || dyi == -2 || dyi == 2) {
                        const int xa = cx - 2 < 0 ? 0 : cx - 2;
                        const int xb = cx + 2 > GD - 1 ? GD - 1 : cx + 2;
                        const int st = cstart[cb + xa], en = cstart[cb + xb + 1];
                        for (int p = st + s; p < en; p += SEG) EVAL_BODY(p, ins_fast)
                    } else {
                        if (cx - 2 >= 0) {
                            const int st = cstart[cb + cx - 2], en = cstart[cb + cx - 1];
                            for (int p = st + s; p < en; p += SEG) EVAL_BODY(p, ins_fast)
                        }
                        if (cx + 2 <= GD - 1) {
                            const int st = cstart[cb + cx + 2], en = cstart[cb + cx + 3];
                            for (int p = st + s; p < en; p += SEG) EVAL_BODY(p, ins_fast)
                        }
                    }
                }
                merge_group8(b0, b1, b2);

                have3 = (b2 != ~0ull);
                b2d = unmono((uint32_t)(b2 >> 32));
                if (!(have3 && (b2d + 1e-4f < 0.0625f))) {
                    for (int p = s; p < NXP; p += SEG) EVAL_BODY(p, ins_dedup)
                    merge_group8(b0, b1, b2);
                }
            }
        }
#undef EVAL_BODY

        const int j[3] = { (int)(uint32_t)b0, (int)(uint32_t)b1, (int)(uint32_t)b2 };
        float w[3];
        #pragma unroll
        for (int i = 0; i < 3; ++i) {
            const int jj = j[i];
            const float dx = __fsub_rn(pos_x[jj*3+0], y0);
            const float dy = __fsub_rn(pos_x[jj*3+1], y1);
            const float dz = __fsub_rn(pos_x[jj*3+2], y2);
            const float sq = __fadd_rn(__fadd_rn(__fmul_rn(dx, dx), __fmul_rn(dy, dy)),
                                       __fmul_rn(dz, dz));
            w[i] = 1.0f / fmaxf(sq, 1e-16f);
        }
        const float inv_den = 1.0f / __fadd_rn(__fadd_rn(w[0], w[1]), w[2]);

        const float2* x2 = (const float2*)x;
        float2* o2 = (float2*)out;
        const float2 a = x2[j[0]*8 + s];
        const float2 b = x2[j[1]*8 + s];
        const float2 c = x2[j[2]*8 + s];
        float2 rr;
        rr.x = (w[0]*a.x + w[1]*b.x + w[2]*c.x) * inv_den;
        rr.y = (w[0]*a.y + w[1]*b.y + w[2]*c.y) * inv_den;
        o2[q*8 + s] = rr;
    }
}

extern "C" void kernel_launch(void* const* d_in, const int* in_sizes, int n_in,
                              void* d_out, int out_size, void* d_ws, size_t ws_size,
                              hipStream_t stream) {
    const float* x     = (const float*)d_in[0];  // [2048, 16]
    const float* pos_x = (const float*)d_in[1];  // [2048, 3]
    const float* pos_y = (const float*)d_in[2];  // [65536, 3]
    float* out = (float*)d_out;
    const int ny = in_sizes[2] / 3;  // 65536

    float4*         wspt   = (float4*)        ((char*)d_ws + WS_SPT);
    int*            wsidx  = (int*)           ((char*)d_ws + WS_SIDX);
    int*            wcst   = (int*)           ((char*)d_ws + WS_CST);
    unsigned short* scan2d = (unsigned short*)((char*)d_ws + WS_SCN);
    unsigned short* qsrt   = (unsigned short*)((char*)d_ws + WS_QSRT);

    if (ws_size >= (size_t)WS_NEED && ny <= NQB * BQ) {
        build_scatter<<<1 + NQB, 512, 0, stream>>>(pos_x, pos_y, ny,
                                                   wspt, wsidx, wcst, scan2d, qsrt);
        knn_cell<<<NCELL * 2, 512, 0, stream>>>(x, pos_x, pos_y, wspt, wsidx, wcst,
                                                scan2d, qsrt, out);
    } else {
        build_scatter<<<1, 512, 0, stream>>>(pos_x, pos_y, 0,
                                             wspt, wsidx, wcst, scan2d, qsrt);
        knn_query_fb<<<QGRID, QBLK, 0, stream>>>(x, pos_x, pos_y, wspt, wsidx, wcst,
                                                 out, ny);
    }
}

// Round 19
// 28.517 us; speedup vs baseline: 1.3710x; 1.3710x over previous
//
#include <hip/hip_runtime.h>
#include <stdint.h>

#define NXP   2048   // pivotal (source) nodes
#define NC    16     // feature channels
#define GD    8      // grid cells per axis
#define NCELL (GD*GD*GD)   // 512
#define CAP   512    // max staged candidates per cell block
#define QCAP  512    // query LDS list capacity per pass
#define HCELL 0.125f
#define NQB   128    // query scatter blocks
#define BQ    512    // queries per scatter block

// ---- d_ws layout (bytes); total 305472 <= 312832 (proven available, r9) ----
#define WS_SPT   0        // float4[2048]
#define WS_SIDX  32768    // int[2048]
#define WS_CST   40960    // int[513]                     (ends 43012)
#define WS_SCN   43072    // u16[128][513] per-block cell scan (ends 174400)
#define WS_QSRT  174400   // u16[65536] block-sorted query ids (ends 305472)
#define WS_NEED  305472

__device__ __forceinline__ int cell_of(float v) {
    int c = (int)(v * (float)GD);
    c = c > GD - 1 ? GD - 1 : c;
    return c < 0 ? 0 : c;
}
__device__ __forceinline__ uint32_t mono(float d) {
    uint32_t b = __float_as_uint(d);
    return b ^ (uint32_t)(((int32_t)b >> 31) | 0x80000000);
}
__device__ __forceinline__ float unmono(uint32_t m) {
    uint32_t b = (m & 0x80000000u) ? (m ^ 0x80000000u) : ~m;
    return __uint_as_float(b);
}
__device__ __forceinline__ void ins_fast(uint64_t k, uint64_t& b0, uint64_t& b1, uint64_t& b2) {
    const bool lt0 = k < b0, lt1 = k < b1;
    b2 = lt1 ? b1 : k;
    b1 = lt0 ? b0 : (lt1 ? k : b1);
    b0 = lt0 ? k  : b0;
}
__device__ __forceinline__ void ins_dedup(uint64_t k, uint64_t& b0, uint64_t& b1, uint64_t& b2) {
    if (k == b0 || k == b1 || k == b2) return;
    const bool lt0 = k < b0, lt1 = k < b1, lt2 = k < b2;
    b2 = lt1 ? b1 : (lt2 ? k : b2);
    b1 = lt0 ? b0 : (lt1 ? k : b1);
    b0 = lt0 ? k  : b0;
}
__device__ __forceinline__ uint64_t shfl_u64(uint64_t v, int src) {
    const int lo = __shfl((int)(uint32_t)v, src);
    const int hi = __shfl((int)(uint32_t)(v >> 32), src);
    return ((uint64_t)(uint32_t)hi << 32) | (uint32_t)lo;
}
__device__ __forceinline__ uint64_t shfl_xor_u64(uint64_t v, int mask) {
    const int lo = __shfl_xor((int)(uint32_t)v, mask);
    const int hi = __shfl_xor((int)(uint32_t)(v >> 32), mask);
    return ((uint64_t)(uint32_t)hi << 32) | (uint32_t)lo;
}

// ========== K1: block 0 builds point grid; blocks 1..128 LDS-sort queries ==========
__global__ __launch_bounds__(512) void build_scatter(
    const float* __restrict__ pos_x, const float* __restrict__ pos_y, int ny,
    float4* __restrict__ wspt, int* __restrict__ wsidx, int* __restrict__ wcstart,
    unsigned short* __restrict__ scan2d, unsigned short* __restrict__ qsrt)
{
    __shared__ int sA[NCELL];
    __shared__ int sB[NCELL];
    const int t = threadIdx.x;

    if (blockIdx.x == 0) {
        // ---- point grid build (byte-identical to proven r6..r16 code) ----
        sA[t] = 0;
        __syncthreads();

        const float4* px4 = (const float4*)pos_x;
        const float4 v0 = px4[t*3+0], v1 = px4[t*3+1], v2 = px4[t*3+2];
        const float pxx[4] = {v0.x, v0.w, v1.z, v2.y};
        const float pyy[4] = {v0.y, v1.x, v1.w, v2.z};
        const float pzz[4] = {v0.z, v1.y, v2.x, v2.w};
        int cc[4];
        #pragma unroll
        for (int i = 0; i < 4; ++i) {
            cc[i] = (cell_of(pzz[i]) * GD + cell_of(pyy[i])) * GD + cell_of(pxx[i]);
            atomicAdd(&sA[cc[i]], 1);
        }
        __syncthreads();

        if (t < 64) {
            const int base = t * 8;
            int v[8];
            int run = 0;
            #pragma unroll
            for (int i = 0; i < 8; ++i) { run += sA[base + i]; v[i] = run; }
            int xs = run;
            #pragma unroll
            for (int off = 1; off < 64; off <<= 1) {
                const int y = __shfl_up(xs, off);
                if (t >= off) xs += y;
            }
            const int excl = xs - run;
            #pragma unroll
            for (int i = 0; i < 8; ++i) {
                const int inc = excl + v[i];
                wcstart[base + i + 1] = inc;
                sB[base + i] = inc - sA[base + i];
            }
            if (t == 0) wcstart[0] = 0;
        }
        __syncthreads();

        #pragma unroll
        for (int i = 0; i < 4; ++i) {
            const int p = t * 4 + i;
            const int pos = atomicAdd(&sB[cc[i]], 1);
            const float sx = __fadd_rn(__fadd_rn(__fmul_rn(pxx[i], pxx[i]),
                                                 __fmul_rn(pyy[i], pyy[i])),
                                       __fmul_rn(pzz[i], pzz[i]));
            wspt[pos] = make_float4(pxx[i], pyy[i], pzz[i], sx);
            wsidx[pos] = p;
        }
    } else {
        // ---- LDS counting sort of this block's 512 queries (no global atomics) ----
        const int b = blockIdx.x - 1;
        sA[t] = 0;
        __syncthreads();

        const int q = b * BQ + t;
        int c = -1;
        if (q < ny) {
            c = (cell_of(pos_y[q*3+2]) * GD + cell_of(pos_y[q*3+1])) * GD
              + cell_of(pos_y[q*3+0]);
            atomicAdd(&sA[c], 1);     // LDS atomic
        }
        __syncthreads();

        if (t < 64) {
            const int base = t * 8;
            int v[8];
            int run = 0;
            #pragma unroll
            for (int i = 0; i < 8; ++i) { run += sA[base + i]; v[i] = run; }
            int xs = run;
            #pragma unroll
            for (int off = 1; off < 64; off <<= 1) {
                const int y = __shfl_up(xs, off);
                if (t >= off) xs += y;
            }
            const int excl = xs - run;
            #pragma unroll
            for (int i = 0; i < 8; ++i)
                sB[base + i] = excl + v[i] - sA[base + i];   // exclusive start
        }
        __syncthreads();

        scan2d[b * 513 + t] = (unsigned short)sB[t];
        if (t == 0) {
            int nb = ny - b * BQ;
            nb = nb < 0 ? 0 : (nb > BQ ? BQ : nb);
            scan2d[b * 513 + 512] = (unsigned short)nb;
        }
        __syncthreads();

        if (q < ny) {
            const int pos = atomicAdd(&sB[c], 1);   // LDS atomic rank
            qsrt[b * BQ + pos] = (unsigned short)q;
        }
    }
}

// ========== K2: TWO blocks per cell (half the queries each); 4-lane groups ==========
__global__ __launch_bounds__(256) void knn_cell(
    const float* __restrict__ x, const float* __restrict__ pos_x,
    const float* __restrict__ pos_y,
    const float4* __restrict__ wspt, const int* __restrict__ wsidx,
    const int* __restrict__ wcst,
    const unsigned short* __restrict__ scan2d, const unsigned short* __restrict__ qsrt,
    float* __restrict__ out)
{
    __shared__ float4 scand[CAP];
    __shared__ int    scidx[CAP];
    __shared__ int    rst[25], roff[26];
    __shared__ int    sL, sForce;
    __shared__ unsigned short qlist[QCAP];
    __shared__ int    wsum[2];

    const int t = threadIdx.x;
    const int c = blockIdx.x >> 1, half = blockIdx.x & 1;
    const int cx = c & 7, cy = (c >> 3) & 7, cz = c >> 6;
    const int lane = t & 63;   // lane in wave
    const int grp  = t >> 2;   // query group 0..63
    const int s    = t & 3;    // segment within group

    // R=2 only for edge/corner cells (bcnt>=2) — r6/r7-proven rule
    const int bcnt = (int)(cx == 0 || cx == GD-1) + (int)(cy == 0 || cy == GD-1)
                   + (int)(cz == 0 || cz == GD-1);
    const int R  = (bcnt >= 2) ? 2 : 1;
    const int W  = 2 * R + 1;
    const int NR = W * W;

    if (t < NR) {
        const int uz = cz + t / W - R, uy = cy + t % W - R;
        int st = 0, len = 0;
        if (((unsigned)uz < (unsigned)GD) & ((unsigned)uy < (unsigned)GD)) {
            const int xa = cx - R < 0 ? 0 : cx - R;
            const int xb = cx + R > GD - 1 ? GD - 1 : cx + R;
            const int cb = (uz * GD + uy) * GD;
            st  = wcst[cb + xa];
            len = wcst[cb + xb + 1] - st;
        }
        rst[t] = st;
        roff[t] = len;
    }
    __syncthreads();
    if (t == 0) {
        int o = 0;
        #pragma unroll 1
        for (int r = 0; r < NR; ++r) { const int l = roff[r]; roff[r] = o; o += l; }
        roff[NR] = o;
        sL = o > CAP ? CAP : o;
        sForce = (o > CAP) ? 1 : 0;
    }
    __syncthreads();

    // Lpad multiple of 32 (per-lane count multiple of 8); (512+31)&~31 == 512 <= CAP
    const int L = sL, Lpad = (sL + 31) & ~31, force = sForce;
    for (int i = t; i < L; i += 256) {
        int r = 0;
        while (i >= roff[r + 1]) ++r;
        const int src = rst[r] + (i - roff[r]);
        scand[i] = wspt[src];
        scidx[i] = wsidx[src];
    }
    for (int i = L + t; i < Lpad; i += 256) {
        scand[i] = make_float4(0.f, 0.f, 0.f, 3e30f);  // sentinel: never inserted
        scidx[i] = 0x7fffffff;
    }

    // ---- query gather (threads 0..127): lane t = source block; seg [s0, s0+cnt) ----
    int base = 0, cnt = 0, s0 = 0;
    if (t < 128) {
        s0  = (int)scan2d[t * 513 + c];
        cnt = (int)scan2d[t * 513 + c + 1] - s0;
        int inc = cnt;
        #pragma unroll
        for (int off = 1; off < 64; off <<= 1) {
            const int y = __shfl_up(inc, off);
            if (lane >= off) inc += y;
        }
        if (lane == 63) wsum[t >> 6] = inc;
        base = inc - cnt;
    }
    __syncthreads();
    if (t >= 64 && t < 128) base += wsum[0];
    const int total = wsum[0] + wsum[1];

    // this block handles [beg, end) of the cell's query list
    const int mid = (total + 1) >> 1;
    const int beg = half ? mid : 0;
    const int end = half ? total : mid;

    for (int S = 0; S < total; S += QCAP) {
        __syncthreads();
        if (t < 128) {
            for (int k = 0; k < cnt; ++k) {
                const int g = base + k;
                if (g >= S && g < S + QCAP) qlist[g - S] = qsrt[t * BQ + s0 + k];
            }
        }
        __syncthreads();
        // intersect this chunk with [beg, end)
        const int n   = (total - S) < QCAP ? (total - S) : QCAP;
        const int lo  = (beg - S) > 0 ? (beg - S) : 0;
        const int hi  = (end - S) < n ? (end - S) : n;

        for (int i0 = lo; i0 < hi; i0 += 64) {
            const int slot = i0 + grp;
            const bool active = slot < hi;
            const int q = active ? (int)qlist[slot] : 0;
            float y0 = 0.f, y1 = 0.f, y2 = 0.f;
            if (active) { y0 = pos_y[q*3+0]; y1 = pos_y[q*3+1]; y2 = pos_y[q*3+2]; }
            const float sy = __fadd_rn(__fadd_rn(__fmul_rn(y0, y0), __fmul_rn(y1, y1)),
                                       __fmul_rn(y2, y2));

            // exact clearance to staged cube (proven r9..r15)
            float clr = 1e30f;
            if (cx - R > 0)      clr = fminf(clr, y0 - (float)(cx - R) * HCELL);
            if (cx + R < GD - 1) clr = fminf(clr, (float)(cx + R + 1) * HCELL - y0);
            if (cy - R > 0)      clr = fminf(clr, y1 - (float)(cy - R) * HCELL);
            if (cy + R < GD - 1) clr = fminf(clr, (float)(cy + R + 1) * HCELL - y1);
            if (cz - R > 0)      clr = fminf(clr, y2 - (float)(cz - R) * HCELL);
            if (cz + R < GD - 1) clr = fminf(clr, (float)(cz + R + 1) * HCELL - y2);
            const float thr = clr * clr;

            uint64_t b0 = ~0ull, b1 = ~0ull, b2 = ~0ull;

            // ---- phase A: lane scans its quarter (stride-4 interleave),
            // 2-deep pipeline over 4-candidate batches; d2 rounding identical
            // to every passing round.
            const int PL = Lpad >> 2;    // per-lane candidates, multiple of 8
            float4 pA[4]; int iA[4];
            float4 pB[4]; int iB[4];
            #pragma unroll
            for (int u = 0; u < 4; ++u) {
                const int id = s + 4*u;
                pA[u] = scand[id]; iA[u] = scidx[id];
            }

            for (int j = 0; j < PL; j += 8) {
                #pragma unroll
                for (int u = 0; u < 4; ++u) {
                    const int id = s + 4*(j + 4 + u);
                    pB[u] = scand[id]; iB[u] = scidx[id];
                }
                {
                    uint64_t kk[4];
                    #pragma unroll
                    for (int u = 0; u < 4; ++u) {
                        const float dot = __fmaf_rn(y2, pA[u].z,
                                          __fmaf_rn(y1, pA[u].y, __fmul_rn(y0, pA[u].x)));
                        const float d = __fmaf_rn(-2.0f, dot, __fadd_rn(sy, pA[u].w));
                        kk[u] = ((uint64_t)mono(d) << 32) | (uint32_t)iA[u];
                    }
                    #pragma unroll
                    for (int u = 0; u < 4; ++u) {
                        const uint64_t k2 = kk[u];
                        const bool lt0 = k2 < b0, lt1 = k2 < b1, lt2 = k2 < b2;
                        b2 = lt1 ? b1 : (lt2 ? k2 : b2);
                        b1 = lt0 ? b0 : (lt1 ? k2 : b1);
                        b0 = lt0 ? k2 : b0;
                    }
                }
                if (j + 8 < PL) {
                    #pragma unroll
                    for (int u = 0; u < 4; ++u) {
                        const int id = s + 4*(j + 8 + u);
                        pA[u] = scand[id]; iA[u] = scidx[id];
                    }
                }
                {
                    uint64_t kk[4];
                    #pragma unroll
                    for (int u = 0; u < 4; ++u) {
                        const float dot = __fmaf_rn(y2, pB[u].z,
                                          __fmaf_rn(y1, pB[u].y, __fmul_rn(y0, pB[u].x)));
                        const float d = __fmaf_rn(-2.0f, dot, __fadd_rn(sy, pB[u].w));
                        kk[u] = ((uint64_t)mono(d) << 32) | (uint32_t)iB[u];
                    }
                    #pragma unroll
                    for (int u = 0; u < 4; ++u) {
                        const uint64_t k2 = kk[u];
                        const bool lt0 = k2 < b0, lt1 = k2 < b1, lt2 = k2 < b2;
                        b2 = lt1 ? b1 : (lt2 ? k2 : b2);
                        b1 = lt0 ? b0 : (lt1 ? k2 : b1);
                        b0 = lt0 ? k2 : b0;
                    }
                }
            }

            // merge across the 4-lane group (masks 1,2 stay in-group); dedup
            // makes overlap-free merging safe (r5-proven)
            #pragma unroll
            for (int mask = 1; mask < 4; mask <<= 1) {
                const uint64_t r0 = shfl_xor_u64(b0, mask);
                const uint64_t r1 = shfl_xor_u64(b1, mask);
                const uint64_t r2 = shfl_xor_u64(b2, mask);
                ins_dedup(r0, b0, b1, b2);
                ins_dedup(r1, b0, b1, b2);
                ins_dedup(r2, b0, b1, b2);
            }

            // escalation (proven): only group leader flags; wave-coop brute
            bool esc = false;
            if (active && s == 0) {
                const bool have3 = (b2 != ~0ull);
                const float b2d = unmono((uint32_t)(b2 >> 32));
                esc = !(have3 && (b2d + 1e-4f < thr)) | (force != 0);
            }
            unsigned long long bal = __ballot(esc);
            while (bal) {
                const int e = __ffsll(bal) - 1;
                bal &= bal - 1;
                const float ey0 = __shfl(y0, e), ey1 = __shfl(y1, e), ey2 = __shfl(y2, e);
                const float esy = __shfl(sy, e);
                uint64_t m0 = shfl_u64(b0, e), m1 = shfl_u64(b1, e), m2 = shfl_u64(b2, e);
                for (int p = lane; p < NXP; p += 64) {
                    const float4 pt = wspt[p];
                    const float dot = __fmaf_rn(ey2, pt.z,
                                      __fmaf_rn(ey1, pt.y, __fmul_rn(ey0, pt.x)));
                    const float d = __fmaf_rn(-2.0f, dot, __fadd_rn(esy, pt.w));
                    const uint64_t kk = ((uint64_t)mono(d) << 32) | (uint32_t)wsidx[p];
                    if (kk < m2) ins_dedup(kk, m0, m1, m2);
                }
                #pragma unroll
                for (int mask = 1; mask < 64; mask <<= 1) {
                    const uint64_t r0 = shfl_xor_u64(m0, mask);
                    const uint64_t r1 = shfl_xor_u64(m1, mask);
                    const uint64_t r2 = shfl_xor_u64(m2, mask);
                    ins_dedup(r0, m0, m1, m2);
                    ins_dedup(r1, m0, m1, m2);
                    ins_dedup(r2, m0, m1, m2);
                }
                if (lane == e) { b0 = m0; b1 = m1; b2 = m2; }
            }
            // re-broadcast group leader's triple (identity for non-escalated)
            {
                const int ldr = lane & ~3;
                b0 = shfl_u64(b0, ldr);
                b1 = shfl_u64(b1, ldr);
                b2 = shfl_u64(b2, ldr);
            }

            // epilogue: each lane writes channel quarter s (coalesced 64B/query)
            if (active) {
                const int j0 = (int)(uint32_t)b0, j1 = (int)(uint32_t)b1,
                          j2 = (int)(uint32_t)b2;
                float w[3];
                const int jj[3] = { j0, j1, j2 };
                #pragma unroll
                for (int i = 0; i < 3; ++i) {
                    const float dx = __fsub_rn(pos_x[jj[i]*3+0], y0);
                    const float dy = __fsub_rn(pos_x[jj[i]*3+1], y1);
                    const float dz = __fsub_rn(pos_x[jj[i]*3+2], y2);
                    const float sq = __fadd_rn(__fadd_rn(__fmul_rn(dx, dx),
                                                         __fmul_rn(dy, dy)),
                                               __fmul_rn(dz, dz));
                    w[i] = 1.0f / fmaxf(sq, 1e-16f);
                }
                const float inv_den = 1.0f / __fadd_rn(__fadd_rn(w[0], w[1]), w[2]);
                const float4* x4 = (const float4*)x;
                float4* o4 = (float4*)out;
                const float4 a = x4[j0*4 + s];
                const float4 b = x4[j1*4 + s];
                const float4 cc2 = x4[j2*4 + s];
                float4 r;
                r.x = (w[0]*a.x + w[1]*b.x + w[2]*cc2.x) * inv_den;
                r.y = (w[0]*a.y + w[1]*b.y + w[2]*cc2.y) * inv_den;
                r.z = (w[0]*a.z + w[1]*b.z + w[2]*cc2.z) * inv_den;
                r.w = (w[0]*a.w + w[1]*b.w + w[2]*cc2.w) * inv_den;
                o4[q*4 + s] = r;
            }
        }
    }
}

// =============== fallback (round-7 kernel, 43 KB ws; proven 34 us) ===============
#define QBLK  512
#define SEG   8
#define QPB   (QBLK / SEG)
#define QGRID 512

__device__ __forceinline__ void merge_group8(uint64_t& b0, uint64_t& b1, uint64_t& b2) {
    #pragma unroll
    for (int mask = 1; mask < SEG; mask <<= 1) {
        const uint64_t r0 = shfl_xor_u64(b0, mask);
        const uint64_t r1 = shfl_xor_u64(b1, mask);
        const uint64_t r2 = shfl_xor_u64(b2, mask);
        ins_dedup(r0, b0, b1, b2);
        ins_dedup(r1, b0, b1, b2);
        ins_dedup(r2, b0, b1, b2);
    }
}

__global__ __launch_bounds__(QBLK) void knn_query_fb(
    const float* __restrict__ x, const float* __restrict__ pos_x,
    const float* __restrict__ pos_y,
    const float4* __restrict__ wspt, const int* __restrict__ wsidx,
    const int* __restrict__ wcstart,
    float* __restrict__ out, int ny)
{
    __shared__ float4 spt[NXP];
    __shared__ int    sidx[NXP];
    __shared__ int    cstart[NCELL + 1];

    const int t = threadIdx.x;
    for (int i = t; i < NXP; i += QBLK) spt[i] = wspt[i];
    for (int i = t; i < NXP; i += QBLK) sidx[i] = wsidx[i];
    for (int i = t; i < NCELL + 1; i += QBLK) cstart[i] = wcstart[i];
    __syncthreads();

    const int s = t & (SEG - 1);
    const int nbatch = (ny + QPB - 1) / QPB;

    for (int batch = blockIdx.x; batch < nbatch; batch += gridDim.x) {
        const int q = batch * QPB + (t >> 3);
        if (q >= ny) continue;

        const float y0 = pos_y[q*3+0], y1 = pos_y[q*3+1], y2 = pos_y[q*3+2];
        const float sy = __fadd_rn(__fadd_rn(__fmul_rn(y0, y0), __fmul_rn(y1, y1)),
                                   __fmul_rn(y2, y2));
        const int cx = cell_of(y0), cy = cell_of(y1), cz = cell_of(y2);

        uint64_t b0 = ~0ull, b1 = ~0ull, b2 = ~0ull;

#define EVAL_BODY(P, INS)                                                       \
        {                                                                       \
            const float4 pt = spt[P];                                           \
            const float dot = __fmaf_rn(y2, pt.z,                               \
                              __fmaf_rn(y1, pt.y, __fmul_rn(y0, pt.x)));        \
            const float d = __fmaf_rn(-2.0f, dot, __fadd_rn(sy, pt.w));         \
            const uint64_t kk = ((uint64_t)mono(d) << 32) | (uint32_t)sidx[P];  \
            if (kk < b2) INS(kk, b0, b1, b2);                                   \
        }

        const int x0 = cx - 1 < 0 ? 0 : cx - 1;
        const int x1 = cx + 1 > GD - 1 ? GD - 1 : cx + 1;
        #pragma unroll
        for (int r = 0; r < 9; ++r) {
            const int uz = cz + r / 3 - 1, uy = cy + r % 3 - 1;
            int st = 0, en = 0;
            if (((unsigned)uz < (unsigned)GD) & ((unsigned)uy < (unsigned)GD)) {
                const int cb = (uz * GD + uy) * GD;
                st = cstart[cb + x0];
                en = cstart[cb + x1 + 1];
            }
            for (int p = st + s; p < en; p += SEG) EVAL_BODY(p, ins_fast)
        }
        merge_group8(b0, b1, b2);

        {
            bool have3 = (b2 != ~0ull);
            float b2d = unmono((uint32_t)(b2 >> 32));
            if (!(have3 && (b2d + 1e-4f < 0.015625f))) {
                for (int r = 0; r < 25; ++r) {
                    const int dzi = r / 5 - 2, dyi = r % 5 - 2;
                    const int uz = cz + dzi, uy = cy + dyi;
                    if (((unsigned)uz >= (unsigned)GD) | ((unsigned)uy >= (unsigned)GD))
                        continue;
                    const int cb = (uz * GD + uy) * GD;
                    if (dzi == -2 || dzi == 2 || dyi == -2 || dyi == 2) {
                        const int xa = cx - 2 < 0 ? 0 : cx - 2;
                        const int xb = cx + 2 > GD - 1 ? GD - 1 : cx + 2;
                        const int st = cstart[cb + xa], en = cstart[cb + xb + 1];
                        for (int p = st + s; p < en; p += SEG) EVAL_BODY(p, ins_fast)
                    } else {
                        if (cx - 2 >= 0) {
                            const int st = cstart[cb + cx - 2], en = cstart[cb + cx - 1];
                            for (int p = st + s; p < en; p += SEG) EVAL_BODY(p, ins_fast)
                        }
                        if (cx + 2 <= GD - 1) {
                            const int st = cstart[cb + cx + 2], en = cstart[cb + cx + 3];
                            for (int p = st + s; p < en; p += SEG) EVAL_BODY(p, ins_fast)
                        }
                    }
                }
                merge_group8(b0, b1, b2);

                have3 = (b2 != ~0ull);
                b2d = unmono((uint32_t)(b2 >> 32));
                if (!(have3 && (b2d + 1e-4f < 0.0625f))) {
                    for (int p = s; p < NXP; p += SEG) EVAL_BODY(p, ins_dedup)
                    merge_group8(b0, b1, b2);
                }
            }
        }
#undef EVAL_BODY

        const int j[3] = { (int)(uint32_t)b0, (int)(uint32_t)b1, (int)(uint32_t)b2 };
        float w[3];
        #pragma unroll
        for (int i = 0; i < 3; ++i) {
            const int jj = j[i];
            const float dx = __fsub_rn(pos_x[jj*3+0], y0);
            const float dy = __fsub_rn(pos_x[jj*3+1], y1);
            const float dz = __fsub_rn(pos_x[jj*3+2], y2);
            const float sq = __fadd_rn(__fadd_rn(__fmul_rn(dx, dx), __fmul_rn(dy, dy)),
                                       __fmul_rn(dz, dz));
            w[i] = 1.0f / fmaxf(sq, 1e-16f);
        }
        const float inv_den = 1.0f / __fadd_rn(__fadd_rn(w[0], w[1]), w[2]);

        const float2* x2 = (const float2*)x;
        float2* o2 = (float2*)out;
        const float2 a = x2[j[0]*8 + s];
        const float2 b = x2[j[1]*8 + s];
        const float2 c = x2[j[2]*8 + s];
        float2 rr;
        rr.x = (w[0]*a.x + w[1]*b.x + w[2]*c.x) * inv_den;
        rr.y = (w[0]*a.y + w[1]*b.y + w[2]*c.y) * inv_den;
        o2[q*8 + s] = rr;
    }
}

extern "C" void kernel_launch(void* const* d_in, const int* in_sizes, int n_in,
                              void* d_out, int out_size, void* d_ws, size_t ws_size,
                              hipStream_t stream) {
    const float* x     = (const float*)d_in[0];  // [2048, 16]
    const float* pos_x = (const float*)d_in[1];  // [2048, 3]
    const float* pos_y = (const float*)d_in[2];  // [65536, 3]
    float* out = (float*)d_out;
    const int ny = in_sizes[2] / 3;  // 65536

    float4*         wspt   = (float4*)        ((char*)d_ws + WS_SPT);
    int*            wsidx  = (int*)           ((char*)d_ws + WS_SIDX);
    int*            wcst   = (int*)           ((char*)d_ws + WS_CST);
    unsigned short* scan2d = (unsigned short*)((char*)d_ws + WS_SCN);
    unsigned short* qsrt   = (unsigned short*)((char*)d_ws + WS_QSRT);

    if (ws_size >= (size_t)WS_NEED && ny <= NQB * BQ) {
        build_scatter<<<1 + NQB, 512, 0, stream>>>(pos_x, pos_y, ny,
                                                   wspt, wsidx, wcst, scan2d, qsrt);
        knn_cell<<<NCELL * 2, 256, 0, stream>>>(x, pos_x, pos_y, wspt, wsidx, wcst,
                                                scan2d, qsrt, out);
    } else {
        build_scatter<<<1, 512, 0, stream>>>(pos_x, pos_y, 0,
                                             wspt, wsidx, wcst, scan2d, qsrt);
        knn_query_fb<<<QGRID, QBLK, 0, stream>>>(x, pos_x, pos_y, wspt, wsidx, wcst,
                                                 out, ny);
    }
}